// Round 5
// baseline (861.233 us; speedup 1.0000x reference)
//
#include <hip/hip_runtime.h>
#include <cstdint>
#include <cstddef>

typedef __bf16 bf16_t;
typedef __bf16 bf16x8 __attribute__((ext_vector_type(8)));
typedef float floatx4 __attribute__((ext_vector_type(4)));

// ---------------- helpers ----------------
__device__ __forceinline__ float wred_sum(float v) {
#pragma unroll
  for (int off = 32; off > 0; off >>= 1) v += __shfl_xor(v, off);
  return v;
}
__device__ __forceinline__ void async16(const void* g, void* l) {
  __builtin_amdgcn_global_load_lds((const __attribute__((address_space(1))) void*)g,
                                   (__attribute__((address_space(3))) void*)l, 16, 0, 0);
}

// ---------------- generic batched bf16 GEMM (m97 structure) ----------------
template <bool OUT_BF16, bool RESID>
__global__ __launch_bounds__(256) void st_gemm(
    const bf16_t* __restrict__ A, const bf16_t* __restrict__ B, void* Cp,
    const float* Res, int M, int N, int K, int lda, int ldb, int ldc, int nb1,
    long long sa1, long long sa2, long long sb1, long long sb2,
    long long sc1, long long sc2) {
  __shared__ bf16_t sA[128 * 32];
  __shared__ bf16_t sB[128 * 32];
  const int z = blockIdx.z;
  const int z1 = z % nb1, z2 = z / nb1;
  A += z1 * sa1 + z2 * sa2;
  B += z1 * sb1 + z2 * sb2;
  const long long coff = z1 * sc1 + z2 * sc2;
  const int tid = threadIdx.x;
  const int bm = blockIdx.x, bn = blockIdx.y;
  const int lane = tid & 63;
  const int wave = tid >> 6;
  const int wm = (wave >> 1) * 64, wn = (wave & 1) * 64;
  const int rowf = lane & 15, kq = (lane >> 4) * 8;

  floatx4 acc[4][4];
#pragma unroll
  for (int i = 0; i < 4; ++i)
#pragma unroll
    for (int j = 0; j < 4; ++j) acc[i][j] = floatx4{0.f, 0.f, 0.f, 0.f};

  for (int kt = 0; kt < K; kt += 32) {
#pragma unroll
    for (int it = 0; it < 2; ++it) {
      int slot = it * 256 + tid;
      int mi = slot >> 2, kc = slot & 3;
      int ar = bm * 128 + mi; if (ar > M - 1) ar = M - 1;
      int br = bn * 128 + mi; if (br > N - 1) br = N - 1;
      async16(A + (size_t)ar * lda + kt + kc * 8, (char*)sA + slot * 16);
      async16(B + (size_t)br * ldb + kt + kc * 8, (char*)sB + slot * 16);
    }
    __syncthreads();
    bf16x8 af[4], bv[4];
#pragma unroll
    for (int i = 0; i < 4; ++i) {
      af[i] = *(const bf16x8*)(sA + (wm + i * 16 + rowf) * 32 + kq);
      bv[i] = *(const bf16x8*)(sB + (wn + i * 16 + rowf) * 32 + kq);
    }
#pragma unroll
    for (int i = 0; i < 4; ++i)
#pragma unroll
      for (int j = 0; j < 4; ++j)
        acc[i][j] = __builtin_amdgcn_mfma_f32_16x16x32_bf16(af[i], bv[j], acc[i][j], 0, 0, 0);
    __syncthreads();
  }

  const int colBase = bn * 128 + wn + (lane & 15);
  const int rowBase = bm * 128 + wm + (lane >> 4) * 4;
#pragma unroll
  for (int i = 0; i < 4; ++i) {
#pragma unroll
    for (int j = 0; j < 4; ++j) {
      int col = colBase + j * 16;
      if (col >= N) continue;
#pragma unroll
      for (int r = 0; r < 4; ++r) {
        int row = rowBase + i * 16 + r;
        if (row >= M) continue;
        long long idx = coff + (long long)row * ldc + col;
        float v = acc[i][j][r];
        if (RESID) v += Res[idx];
        if (OUT_BF16) ((bf16_t*)Cp)[idx] = (bf16_t)v;
        else          ((float*)Cp)[idx] = v;
      }
    }
  }
}

// ---------------- tiled fp32 transpose (R x C) -> (C x R), batched ----------------
__global__ __launch_bounds__(256) void st_transpose2d(
    const float* __restrict__ in, float* __restrict__ out, int R, int Cc,
    long long inb, long long outb) {
  __shared__ float tile[32][33];
  const int ct = blockIdx.x, rt = blockIdx.y, b = blockIdx.z;
  in += (long long)b * inb;
  out += (long long)b * outb;
  const int tx = threadIdx.x & 31, ty = threadIdx.x >> 5;
#pragma unroll
  for (int k = 0; k < 4; ++k) {
    int r = rt * 32 + ty + k * 8;
    int c = ct * 32 + tx;
    tile[ty + k * 8][tx] = in[(size_t)r * Cc + c];
  }
  __syncthreads();
#pragma unroll
  for (int k = 0; k < 4; ++k) {
    int c = ct * 32 + ty + k * 8;
    int r = rt * 32 + tx;
    out[(size_t)c * R + r] = tile[tx][ty + k * 8];
  }
}

// ---------------- weight transpose fp32 (K x N) -> bf16 (N x Kpad) ----------------
__global__ void st_wtrans(const float* __restrict__ src, bf16_t* __restrict__ dst,
                          int K, int Kpad, int N, int srcld, int coloff, long total) {
  long idx = (long)blockIdx.x * 256 + threadIdx.x;
  if (idx >= total) return;
  int kp = (int)(idx % Kpad);
  int n = (int)(idx / Kpad);
  float v = (kp < K) ? src[(size_t)kp * srcld + coloff + n] : 0.f;
  dst[idx] = (bf16_t)v;
}

// ---------------- CPB MLP tables ----------------
__global__ __launch_bounds__(256) void st_cpb(
    const float* __restrict__ w1, const float* __restrict__ b1,
    const float* __restrict__ w2, const float* __restrict__ b2,
    const float* __restrict__ w3, const float* __restrict__ b3,
    bf16_t* __restrict__ tab2d, float* __restrict__ tab1d, int two_d) {
  const int pos = blockIdx.x, t = threadIdx.x;
  float r0, r1 = 0.f;
  if (two_d) { r0 = (float)(pos / 63 - 31); r1 = (float)(pos % 63 - 31); }
  else { r0 = (float)(pos - 7); }
  __shared__ float sh[256];
  float h = r0 * w1[t] + (two_d ? r1 * w1[256 + t] : 0.f) + b1[t];
  h = h / (1.f + expf(-h));
  sh[t] = h;
  __syncthreads();
  float h2 = b2[t];
  for (int j = 0; j < 256; ++j) h2 += sh[j] * w2[j * 256 + t];
  h2 = h2 / (1.f + expf(-h2));
  __syncthreads();
  sh[t] = h2;
  __syncthreads();
  if (t < 8) {
    float o = b3[t];
    for (int j = 0; j < 256; ++j) o += sh[j] * w3[j * 8 + t];
    if (two_d) tab2d[t * 4000 + pos] = (bf16_t)o;
    else tab1d[t * 15 + pos] = o;
  }
}

// ---------------- RMS norm -> bf16 ----------------
__global__ __launch_bounds__(256) void st_rmsnorm(const float* __restrict__ x,
                                                  const float* __restrict__ gamma,
                                                  bf16_t* __restrict__ y) {
  const int token = blockIdx.x * 4 + (threadIdx.x >> 6);
  const int lane = threadIdx.x & 63;
  const float* xr = x + (size_t)token * 512;
  float v[8];
  float ss = 0.f;
#pragma unroll
  for (int k = 0; k < 8; ++k) { v[k] = xr[k * 64 + lane]; ss += v[k] * v[k]; }
  ss = wred_sum(ss);
  const float r = 22.627416998f / fmaxf(sqrtf(ss), 1e-12f);
  bf16_t* yr = y + (size_t)token * 512;
#pragma unroll
  for (int k = 0; k < 8; ++k) yr[k * 64 + lane] = (bf16_t)(v[k] * r * gamma[k * 64 + lane]);
}

// ---------------- V transpose: qkv -> vT[(bf*8+h)][d][j] ----------------
__global__ __launch_bounds__(256) void st_vtrans(const bf16_t* __restrict__ qkv,
                                                 bf16_t* __restrict__ vT) {
  __shared__ float tile[32][33];
  const int jt = blockIdx.x, dt = blockIdx.y, z = blockIdx.z;
  const int bf = z >> 3, h = z & 7;
  const int tx = threadIdx.x & 31, ty = threadIdx.x >> 5;
#pragma unroll
  for (int k = 0; k < 4; ++k) {
    int j = jt * 32 + ty + k * 8;
    int d = dt * 32 + tx;
    tile[ty + k * 8][tx] = (float)qkv[((size_t)(bf * 1024 + j)) * 1536 + 1024 + h * 64 + d];
  }
  __syncthreads();
#pragma unroll
  for (int k = 0; k < 4; ++k) {
    int d = dt * 32 + ty + k * 8;
    int j = jt * 32 + tx;
    vT[((size_t)z * 64 + d) * 1024 + j] = (bf16_t)tile[tx][ty + k * 8];
  }
}

// ---------------- fused flash spatial attention (R5: barrier-free K-loop) ----------------
// grid (x=z=128, y=qtile=8): XCD = z%8 -> all qtiles of a z share one XCD L2.
// R4 was latency-bound (all pipes <20%): 2 barriers/iter with vmcnt(0) drains +
// ~84 LDS ops/wave/iter on a shared LDS pipe at 4 waves/SIMD. R5: K and V
// B-operand fragments are read DIRECTLY from global (16B/lane dwordx4; L2-hot,
// reused 32x per XCD) -> no K/V LDS staging, no in-loop __syncthreads at all.
// LDS keeps only the read-only bias table + wave-private P round-trip (intra-
// wave lgkmcnt ordering only). LDS 37.4->20.4 KB.
__global__ __launch_bounds__(256, 4) void st_flash(
    const bf16_t* __restrict__ qkv, const bf16_t* __restrict__ vT,
    const bf16_t* __restrict__ tabb, bf16_t* __restrict__ ob) {
  __shared__ __align__(16) bf16_t ldsP[4 * 32 * 64];
  __shared__ __align__(16) bf16_t ldsT[2216];
  const int z = blockIdx.x;
  const int qtile = blockIdx.y;
  const int bf = z >> 3, h = z & 7;
  const int tid = threadIdx.x;
  const int lane = tid & 63, wave = tid >> 6;
  const int cl = lane & 15, g = lane >> 4;
  const size_t qkvBase = (size_t)bf * 1024 * 1536 + h * 64;
  const int eoff = (qtile * 252) & ~7;

  // stage restricted bias table (277 granules), one-time barrier below
#pragma unroll
  for (int it = 0; it < 2; ++it) {
    int slot = it * 256 + tid;
    if (slot < 277)
      async16(tabb + h * 4000 + eoff + slot * 8, (char*)ldsT + slot * 16);
  }
  // Q A-frags directly from global into registers
  bf16x8 aq[2][2];
#pragma unroll
  for (int it = 0; it < 2; ++it)
#pragma unroll
    for (int ks = 0; ks < 2; ++ks) {
      int row = qtile * 128 + wave * 32 + it * 16 + cl;
      aq[it][ks] = *(const bf16x8*)(qkv + qkvBase + (size_t)row * 1536 + (g + ks * 4) * 8);
    }
  int fiB[2][4];
#pragma unroll
  for (int it = 0; it < 2; ++it)
#pragma unroll
    for (int r = 0; r < 4; ++r) {
      int i = qtile * 128 + wave * 32 + it * 16 + g * 4 + r;
      fiB[it][r] = (i >> 5) * 63 + (i & 31) + 1984 - eoff;
    }
  float lsum[2][4];
  floatx4 oacc[2][4];
#pragma unroll
  for (int it = 0; it < 2; ++it)
#pragma unroll
    for (int r = 0; r < 4; ++r) lsum[it][r] = 0.f;
#pragma unroll
  for (int it = 0; it < 2; ++it)
#pragma unroll
    for (int dt = 0; dt < 4; ++dt) oacc[it][dt] = floatx4{0.f, 0.f, 0.f, 0.f};

  bf16_t* ldsPw = ldsP + wave * (32 * 64);
  const bf16_t* Kp = qkv + qkvBase + 512;
  const bf16_t* Vp = vT + (size_t)z * 65536;

  __syncthreads();  // ldsT visible (drains the global_load_lds)

  for (int j0 = 0; j0 < 1024; j0 += 64) {
    // S = Q K^T : K B-frags direct from global, per-ks to bound VGPR pressure
    floatx4 sacc[2][4];
#pragma unroll
    for (int it = 0; it < 2; ++it)
#pragma unroll
      for (int jt = 0; jt < 4; ++jt) sacc[it][jt] = floatx4{0.f, 0.f, 0.f, 0.f};
#pragma unroll
    for (int ks = 0; ks < 2; ++ks) {
      bf16x8 kf[4];
#pragma unroll
      for (int jt = 0; jt < 4; ++jt)
        kf[jt] = *(const bf16x8*)(Kp + (size_t)(j0 + jt * 16 + cl) * 1536 + (g + ks * 4) * 8);
#pragma unroll
      for (int jt = 0; jt < 4; ++jt)
#pragma unroll
        for (int it = 0; it < 2; ++it)
          sacc[it][jt] = __builtin_amdgcn_mfma_f32_16x16x32_bf16(aq[it][ks], kf[jt], sacc[it][jt], 0, 0, 0);
    }
    // V B-frags for ks=0 issued early to overlap with the epilogue chain
    bf16x8 vf0[4];
#pragma unroll
    for (int dt = 0; dt < 4; ++dt)
      vf0[dt] = *(const bf16x8*)(Vp + (size_t)(dt * 16 + cl) * 1024 + j0 + g * 8);
    // bias + exp + row-sum, P -> wave-private swizzled LDS
#pragma unroll
    for (int jt = 0; jt < 4; ++jt) {
      int j = j0 + jt * 16 + cl;
      int fj = (j >> 5) * 63 + (j & 31);
      int pg = (jt * 2 + (cl >> 3));
#pragma unroll
      for (int it = 0; it < 2; ++it) {
#pragma unroll
        for (int r = 0; r < 4; ++r) {
          float e = __expf(sacc[it][jt][r] * 0.125f + (float)ldsT[fiB[it][r] - fj]);
          lsum[it][r] += e;
          int prow = it * 16 + g * 4 + r;
          ldsPw[prow * 64 + (pg ^ (prow & 7)) * 8 + (cl & 7)] = (bf16_t)e;
        }
      }
    }
    // O += P V   (wave-private P; lgkmcnt orders write->read, no barrier)
    bf16x8 vf1[4];
#pragma unroll
    for (int dt = 0; dt < 4; ++dt)
      vf1[dt] = *(const bf16x8*)(Vp + (size_t)(dt * 16 + cl) * 1024 + j0 + (4 + g) * 8);
    {
      bf16x8 ap[2];
#pragma unroll
      for (int it = 0; it < 2; ++it)
        ap[it] = *(const bf16x8*)(ldsPw + (it * 16 + cl) * 64 + (g ^ (cl & 7)) * 8);
#pragma unroll
      for (int dt = 0; dt < 4; ++dt)
#pragma unroll
        for (int it = 0; it < 2; ++it)
          oacc[it][dt] = __builtin_amdgcn_mfma_f32_16x16x32_bf16(ap[it], vf0[dt], oacc[it][dt], 0, 0, 0);
#pragma unroll
      for (int it = 0; it < 2; ++it)
        ap[it] = *(const bf16x8*)(ldsPw + (it * 16 + cl) * 64 + ((4 + g) ^ (cl & 7)) * 8);
#pragma unroll
      for (int dt = 0; dt < 4; ++dt)
#pragma unroll
        for (int it = 0; it < 2; ++it)
          oacc[it][dt] = __builtin_amdgcn_mfma_f32_16x16x32_bf16(ap[it], vf1[dt], oacc[it][dt], 0, 0, 0);
    }
  }
  // normalize + write
#pragma unroll
  for (int it = 0; it < 2; ++it)
#pragma unroll
    for (int r = 0; r < 4; ++r) {
#pragma unroll
      for (int x = 1; x < 16; x <<= 1) lsum[it][r] += __shfl_xor(lsum[it][r], x);
      lsum[it][r] = 1.f / lsum[it][r];
    }
#pragma unroll
  for (int it = 0; it < 2; ++it) {
#pragma unroll
    for (int r = 0; r < 4; ++r) {
      int i = qtile * 128 + wave * 32 + it * 16 + g * 4 + r;
      size_t base = ((size_t)bf * 1024 + i) * 512 + h * 64;
#pragma unroll
      for (int dt = 0; dt < 4; ++dt)
        ob[base + dt * 16 + cl] = (bf16_t)(oacc[it][dt][r] * lsum[it][r]);
    }
  }
}

// ---------------- temporal attention (seq=8), log-transpose reduce ----------------
__global__ __launch_bounds__(256) void st_tattn2(const bf16_t* __restrict__ qkv,
                                                 const float* __restrict__ tabf,
                                                 bf16_t* __restrict__ o) {
  const int wg = blockIdx.x * 4 + (threadIdx.x >> 6);
  const int bhw = wg >> 3, head = wg & 7;
  const int lane = threadIdx.x & 63;
  const size_t base = (size_t)bhw * 8 * 1536 + head * 64 + lane;
  float q[8], k[8], v[8];
#pragma unroll
  for (int f = 0; f < 8; ++f) {
    q[f] = (float)qkv[base + (size_t)f * 1536];
    k[f] = (float)qkv[base + (size_t)f * 1536 + 512];
    v[f] = (float)qkv[base + (size_t)f * 1536 + 1024];
  }
  float p[64];
#pragma unroll
  for (int i = 0; i < 8; ++i)
#pragma unroll
    for (int j = 0; j < 8; ++j) p[i * 8 + j] = q[i] * k[j];
#pragma unroll
  for (int st = 32; st >= 1; st >>= 1) {
    const bool hi = (lane & st) != 0;
#pragma unroll
    for (int m = 0; m < st; ++m) {
      float give = hi ? p[m] : p[m + st];
      float keep = hi ? p[m + st] : p[m];
      p[m] = keep + __shfl_xor(give, st);
    }
  }
  const int i = lane >> 3, j = lane & 7;
  float e = __expf(p[0] * 0.125f + tabf[head * 15 + i - j + 7]);
  float sm = e;
  sm += __shfl_xor(sm, 1);
  sm += __shfl_xor(sm, 2);
  sm += __shfl_xor(sm, 4);
  const float prob = e / sm;
  float acc[8];
#pragma unroll
  for (int ii = 0; ii < 8; ++ii) acc[ii] = 0.f;
#pragma unroll
  for (int ii = 0; ii < 8; ++ii)
#pragma unroll
    for (int jj = 0; jj < 8; ++jj)
      acc[ii] += __shfl(prob, ii * 8 + jj) * v[jj];
#pragma unroll
  for (int ii = 0; ii < 8; ++ii)
    o[(size_t)(bhw * 8 + ii) * 512 + head * 64 + lane] = (bf16_t)acc[ii];
}

// ---------------- permute (b,f,hw,c) <-> (b,hw,f,c), optional fused bf16 cast ----------------
__global__ void st_permute(const float* __restrict__ in, float* __restrict__ out, int dir,
                           bf16_t* __restrict__ out2) {
  size_t idx = (size_t)blockIdx.x * 256 + threadIdx.x;
  int c = (int)(idx & 511);
  size_t r = idx >> 9;
  size_t src;
  if (dir == 0) {
    int f = (int)(r & 7);
    int hw = (int)((r >> 3) & 1023);
    int b = (int)(r >> 13);
    src = ((((size_t)b * 8 + f) * 1024 + hw) << 9) + c;
  } else {
    int hw = (int)(r & 1023);
    int f = (int)((r >> 10) & 7);
    int b = (int)(r >> 13);
    src = ((((size_t)b * 1024 + hw) * 8 + f) << 9) + c;
  }
  float v = in[src];
  out[idx] = v;
  if (out2) out2[idx] = (bf16_t)v;
}

// ---------------- GeGLU + temporal shift + RMS -> yn bf16 (K padded to 1376) ----------------
__global__ __launch_bounds__(256) void st_glu(const bf16_t* __restrict__ hdn,
                                              const float* __restrict__ gamma,
                                              bf16_t* __restrict__ yn) {
  const int t = blockIdx.x;
  const int tid = threadIdx.x;
  const int f = (t >> 10) & 7;
  float y[6];
  float ss = 0.f;
#pragma unroll
  for (int kk = 0; kk < 6; ++kk) {
    int c = kk * 256 + tid;
    float yv = 0.f;
    if (c < 1365) {
      long src = t;
      bool valid = true;
      if (c >= 683) { if (f == 0) valid = false; else src = t - 1024; }
      if (valid) {
        float av = (float)hdn[src * 2730 + c];
        float gv = (float)hdn[src * 2730 + 1365 + c];
        yv = av * 0.5f * gv * (1.f + erff(gv * 0.70710678f));
      }
    }
    y[kk] = yv;
    ss += yv * yv;
  }
  __shared__ float red[4];
  ss = wred_sum(ss);
  if ((tid & 63) == 0) red[tid >> 6] = ss;
  __syncthreads();
  ss = red[0] + red[1] + red[2] + red[3];
  const float r = sqrtf(1365.f) / fmaxf(sqrtf(ss), 1e-12f);
#pragma unroll
  for (int kk = 0; kk < 6; ++kk) {
    int c = kk * 256 + tid;
    if (c < 1365) yn[(size_t)t * 1376 + c] = (bf16_t)(y[kk] * r * gamma[c]);
  }
  if (tid < 11) yn[(size_t)t * 1376 + 1365 + tid] = (bf16_t)0.f;
}

// ---------------- launcher ----------------
extern "C" void kernel_launch(void* const* d_in, const int* in_sizes, int n_in,
                              void* d_out, int out_size, void* d_ws, size_t ws_size,
                              hipStream_t stream) {
  const float* x        = (const float*)d_in[0];
  const float* sa_gamma = (const float*)d_in[1];
  const float* sa_wq    = (const float*)d_in[2];
  const float* sa_wkv   = (const float*)d_in[3];
  const float* sa_wo    = (const float*)d_in[4];
  const float* ta_gamma = (const float*)d_in[5];
  const float* ta_wq    = (const float*)d_in[6];
  const float* ta_wkv   = (const float*)d_in[7];
  const float* ta_wo    = (const float*)d_in[8];
  const float* sp_w1 = (const float*)d_in[9];
  const float* sp_b1 = (const float*)d_in[10];
  const float* sp_w2 = (const float*)d_in[11];
  const float* sp_b2 = (const float*)d_in[12];
  const float* sp_w3 = (const float*)d_in[13];
  const float* sp_b3 = (const float*)d_in[14];
  const float* tp_w1 = (const float*)d_in[15];
  const float* tp_b1 = (const float*)d_in[16];
  const float* tp_w2 = (const float*)d_in[17];
  const float* tp_b2 = (const float*)d_in[18];
  const float* tp_w3 = (const float*)d_in[19];
  const float* tp_b3 = (const float*)d_in[20];
  const float* ff_win   = (const float*)d_in[21];
  const float* ff_gamma = (const float*)d_in[22];
  const float* ff_wout  = (const float*)d_in[23];
  float* outp = (float*)d_out;

  char* ws = (char*)d_ws;
  size_t off = 0;
  auto alloc = [&](size_t bytes) -> char* {
    char* p = ws + off;
    off += (bytes + 255) & ~(size_t)255;
    return p;
  };
  const long T = 16384;
  float*  xs  = (float*)alloc((size_t)T * 512 * 4);    // residual stream
  bf16_t* xn  = (bf16_t*)alloc((size_t)T * 512 * 2);   // normed input
  char*   R2  = alloc((size_t)T * 1536 * 2);           // qkv | FF: hdn (spans R2+R3)
  char*   R3  = alloc((size_t)T * 1536 * 2);           // vT+ob | xt+ob | hdn tail
  bf16_t* ynb = (bf16_t*)alloc((size_t)T * 1376 * 2);
  bf16_t* wqkvT_sa = (bf16_t*)alloc(1536ULL * 512 * 2);
  bf16_t* woT_sa   = (bf16_t*)alloc(512ULL * 512 * 2);
  bf16_t* wqkvT_ta = (bf16_t*)alloc(1536ULL * 512 * 2);
  bf16_t* woT_ta   = (bf16_t*)alloc(512ULL * 512 * 2);
  bf16_t* winT  = (bf16_t*)alloc(2730ULL * 512 * 2);
  bf16_t* woutT = (bf16_t*)alloc(512ULL * 1376 * 2);
  bf16_t* tabb  = (bf16_t*)alloc(8 * 4000 * 2);
  float*  tabf  = (float*)alloc(8 * 15 * 4);

  bf16_t* qkv  = (bf16_t*)R2;
  bf16_t* hdn  = (bf16_t*)R2;                       // FF: 16384x2730 bf16 = 85.3MB <= R2+R3 (96MB)
  bf16_t* vT   = (bf16_t*)R3;                       // spatial
  bf16_t* ob_s = (bf16_t*)(R3 + (size_t)T * 512 * 2);
  float*  xt   = (float*)R3;                        // temporal
  bf16_t* ob_t = (bf16_t*)(R3 + (size_t)T * 512 * 4);

  // 1) input: per b transpose (512 x 8192) -> (8192 x 512)
  st_transpose2d<<<dim3(256, 16, 2), 256, 0, stream>>>(x, xs, 512, 8192,
                                                       (long long)512 * 8192, (long long)512 * 8192);
  // 2) weight transposes
  auto wt = [&](const float* src, bf16_t* dst, int K, int Kpad, int N, int srcld, int coloff) {
    long tot = (long)N * Kpad;
    st_wtrans<<<dim3((tot + 255) / 256), 256, 0, stream>>>(src, dst, K, Kpad, N, srcld, coloff, tot);
  };
  wt(sa_wq, wqkvT_sa, 512, 512, 512, 512, 0);
  wt(sa_wkv, wqkvT_sa + 512 * 512, 512, 512, 1024, 1024, 0);
  wt(sa_wo, woT_sa, 512, 512, 512, 512, 0);
  wt(ta_wq, wqkvT_ta, 512, 512, 512, 512, 0);
  wt(ta_wkv, wqkvT_ta + 512 * 512, 512, 512, 1024, 1024, 0);
  wt(ta_wo, woT_ta, 512, 512, 512, 512, 0);
  wt(ff_win, winT, 512, 512, 2730, 2730, 0);
  wt(ff_wout, woutT, 1365, 1376, 512, 512, 0);
  // 3) CPB tables
  st_cpb<<<dim3(3969), 256, 0, stream>>>(sp_w1, sp_b1, sp_w2, sp_b2, sp_w3, sp_b3, tabb, tabf, 1);
  st_cpb<<<dim3(15), 256, 0, stream>>>(tp_w1, tp_b1, tp_w2, tp_b2, tp_w3, tp_b3, tabb, tabf, 0);

  // ---- spatial attention ----
  st_rmsnorm<<<dim3(4096), 256, 0, stream>>>(xs, sa_gamma, xn);
  st_gemm<true, false><<<dim3(128, 12, 1), 256, 0, stream>>>(
      xn, wqkvT_sa, (void*)qkv, nullptr, 16384, 1536, 512, 512, 512, 1536, 1, 0, 0, 0, 0, 0, 0);
  st_vtrans<<<dim3(32, 2, 128), 256, 0, stream>>>(qkv, vT);
  st_flash<<<dim3(128, 8), 256, 0, stream>>>(qkv, vT, tabb, ob_s);
  st_gemm<false, true><<<dim3(128, 4, 1), 256, 0, stream>>>(
      ob_s, woT_sa, (void*)xs, xs, 16384, 512, 512, 512, 512, 512, 1, 0, 0, 0, 0, 0, 0);

  // ---- temporal attention ----
  st_permute<<<dim3(32768), 256, 0, stream>>>(xs, xt, 0, nullptr);
  st_rmsnorm<<<dim3(4096), 256, 0, stream>>>(xt, ta_gamma, xn);
  st_gemm<true, false><<<dim3(128, 12, 1), 256, 0, stream>>>(
      xn, wqkvT_ta, (void*)qkv, nullptr, 16384, 1536, 512, 512, 512, 1536, 1, 0, 0, 0, 0, 0, 0);
  st_tattn2<<<dim3(4096), 256, 0, stream>>>(qkv, tabf, ob_t);
  st_gemm<false, true><<<dim3(128, 4, 1), 256, 0, stream>>>(
      ob_t, woT_ta, (void*)xt, xt, 16384, 512, 512, 512, 512, 512, 1, 0, 0, 0, 0, 0, 0);
  st_permute<<<dim3(32768), 256, 0, stream>>>(xt, xs, 1, xn);  // fused residual copy + cast

  // ---- feed-forward ----
  st_gemm<true, false><<<dim3(128, 22, 1), 256, 0, stream>>>(
      xn, winT, (void*)hdn, nullptr, 16384, 2730, 512, 512, 512, 2730, 1, 0, 0, 0, 0, 0, 0);
  st_glu<<<dim3(16384), 256, 0, stream>>>(hdn, ff_gamma, ynb);
  st_gemm<false, true><<<dim3(128, 4, 1), 256, 0, stream>>>(
      ynb, woutT, (void*)xs, xs, 16384, 512, 1376, 1376, 1376, 512, 1, 0, 0, 0, 0, 0, 0);

  // ---- output: per b transpose (8192 x 512) -> (512 x 8192) ----
  st_transpose2d<<<dim3(16, 256, 2), 256, 0, stream>>>(xs, outp, 8192, 512,
                                                       (long long)8192 * 512, (long long)8192 * 512);
}

// Round 6
// 743.692 us; speedup vs baseline: 1.1581x; 1.1581x over previous
//
#include <hip/hip_runtime.h>
#include <cstdint>
#include <cstddef>

typedef __bf16 bf16_t;
typedef __bf16 bf16x8 __attribute__((ext_vector_type(8)));
typedef float floatx4 __attribute__((ext_vector_type(4)));

// ---------------- helpers ----------------
__device__ __forceinline__ float wred_sum(float v) {
#pragma unroll
  for (int off = 32; off > 0; off >>= 1) v += __shfl_xor(v, off);
  return v;
}
__device__ __forceinline__ void async16(const void* g, void* l) {
  __builtin_amdgcn_global_load_lds((const __attribute__((address_space(1))) void*)g,
                                   (__attribute__((address_space(3))) void*)l, 16, 0, 0);
}

// ---------------- generic batched bf16 GEMM (m97 structure) ----------------
template <bool OUT_BF16, bool RESID>
__global__ __launch_bounds__(256) void st_gemm(
    const bf16_t* __restrict__ A, const bf16_t* __restrict__ B, void* Cp,
    const float* Res, int M, int N, int K, int lda, int ldb, int ldc, int nb1,
    long long sa1, long long sa2, long long sb1, long long sb2,
    long long sc1, long long sc2) {
  __shared__ bf16_t sA[128 * 32];
  __shared__ bf16_t sB[128 * 32];
  const int z = blockIdx.z;
  const int z1 = z % nb1, z2 = z / nb1;
  A += z1 * sa1 + z2 * sa2;
  B += z1 * sb1 + z2 * sb2;
  const long long coff = z1 * sc1 + z2 * sc2;
  const int tid = threadIdx.x;
  const int bm = blockIdx.x, bn = blockIdx.y;
  const int lane = tid & 63;
  const int wave = tid >> 6;
  const int wm = (wave >> 1) * 64, wn = (wave & 1) * 64;
  const int rowf = lane & 15, kq = (lane >> 4) * 8;

  floatx4 acc[4][4];
#pragma unroll
  for (int i = 0; i < 4; ++i)
#pragma unroll
    for (int j = 0; j < 4; ++j) acc[i][j] = floatx4{0.f, 0.f, 0.f, 0.f};

  for (int kt = 0; kt < K; kt += 32) {
#pragma unroll
    for (int it = 0; it < 2; ++it) {
      int slot = it * 256 + tid;
      int mi = slot >> 2, kc = slot & 3;
      int ar = bm * 128 + mi; if (ar > M - 1) ar = M - 1;
      int br = bn * 128 + mi; if (br > N - 1) br = N - 1;
      async16(A + (size_t)ar * lda + kt + kc * 8, (char*)sA + slot * 16);
      async16(B + (size_t)br * ldb + kt + kc * 8, (char*)sB + slot * 16);
    }
    __syncthreads();
    bf16x8 af[4], bv[4];
#pragma unroll
    for (int i = 0; i < 4; ++i) {
      af[i] = *(const bf16x8*)(sA + (wm + i * 16 + rowf) * 32 + kq);
      bv[i] = *(const bf16x8*)(sB + (wn + i * 16 + rowf) * 32 + kq);
    }
#pragma unroll
    for (int i = 0; i < 4; ++i)
#pragma unroll
      for (int j = 0; j < 4; ++j)
        acc[i][j] = __builtin_amdgcn_mfma_f32_16x16x32_bf16(af[i], bv[j], acc[i][j], 0, 0, 0);
    __syncthreads();
  }

  const int colBase = bn * 128 + wn + (lane & 15);
  const int rowBase = bm * 128 + wm + (lane >> 4) * 4;
#pragma unroll
  for (int i = 0; i < 4; ++i) {
#pragma unroll
    for (int j = 0; j < 4; ++j) {
      int col = colBase + j * 16;
      if (col >= N) continue;
#pragma unroll
      for (int r = 0; r < 4; ++r) {
        int row = rowBase + i * 16 + r;
        if (row >= M) continue;
        long long idx = coff + (long long)row * ldc + col;
        float v = acc[i][j][r];
        if (RESID) v += Res[idx];
        if (OUT_BF16) ((bf16_t*)Cp)[idx] = (bf16_t)v;
        else          ((float*)Cp)[idx] = v;
      }
    }
  }
}

// ---------------- tiled fp32 transpose (R x C) -> (C x R), batched ----------------
__global__ __launch_bounds__(256) void st_transpose2d(
    const float* __restrict__ in, float* __restrict__ out, int R, int Cc,
    long long inb, long long outb) {
  __shared__ float tile[32][33];
  const int ct = blockIdx.x, rt = blockIdx.y, b = blockIdx.z;
  in += (long long)b * inb;
  out += (long long)b * outb;
  const int tx = threadIdx.x & 31, ty = threadIdx.x >> 5;
#pragma unroll
  for (int k = 0; k < 4; ++k) {
    int r = rt * 32 + ty + k * 8;
    int c = ct * 32 + tx;
    tile[ty + k * 8][tx] = in[(size_t)r * Cc + c];
  }
  __syncthreads();
#pragma unroll
  for (int k = 0; k < 4; ++k) {
    int c = ct * 32 + ty + k * 8;
    int r = rt * 32 + tx;
    out[(size_t)c * R + r] = tile[tx][ty + k * 8];
  }
}

// ---------------- weight transpose fp32 (K x N) -> bf16 (N x Kpad) ----------------
__global__ void st_wtrans(const float* __restrict__ src, bf16_t* __restrict__ dst,
                          int K, int Kpad, int N, int srcld, int coloff, long total) {
  long idx = (long)blockIdx.x * 256 + threadIdx.x;
  if (idx >= total) return;
  int kp = (int)(idx % Kpad);
  int n = (int)(idx / Kpad);
  float v = (kp < K) ? src[(size_t)kp * srcld + coloff + n] : 0.f;
  dst[idx] = (bf16_t)v;
}

// ---------------- CPB MLP tables ----------------
__global__ __launch_bounds__(256) void st_cpb(
    const float* __restrict__ w1, const float* __restrict__ b1,
    const float* __restrict__ w2, const float* __restrict__ b2,
    const float* __restrict__ w3, const float* __restrict__ b3,
    bf16_t* __restrict__ tab2d, float* __restrict__ tab1d, int two_d) {
  const int pos = blockIdx.x, t = threadIdx.x;
  float r0, r1 = 0.f;
  if (two_d) { r0 = (float)(pos / 63 - 31); r1 = (float)(pos % 63 - 31); }
  else { r0 = (float)(pos - 7); }
  __shared__ float sh[256];
  float h = r0 * w1[t] + (two_d ? r1 * w1[256 + t] : 0.f) + b1[t];
  h = h / (1.f + expf(-h));
  sh[t] = h;
  __syncthreads();
  float h2 = b2[t];
  for (int j = 0; j < 256; ++j) h2 += sh[j] * w2[j * 256 + t];
  h2 = h2 / (1.f + expf(-h2));
  __syncthreads();
  sh[t] = h2;
  __syncthreads();
  if (t < 8) {
    float o = b3[t];
    for (int j = 0; j < 256; ++j) o += sh[j] * w3[j * 8 + t];
    if (two_d) tab2d[t * 4000 + pos] = (bf16_t)o;
    else tab1d[t * 15 + pos] = o;
  }
}

// ---------------- RMS norm -> bf16 ----------------
__global__ __launch_bounds__(256) void st_rmsnorm(const float* __restrict__ x,
                                                  const float* __restrict__ gamma,
                                                  bf16_t* __restrict__ y) {
  const int token = blockIdx.x * 4 + (threadIdx.x >> 6);
  const int lane = threadIdx.x & 63;
  const float* xr = x + (size_t)token * 512;
  float v[8];
  float ss = 0.f;
#pragma unroll
  for (int k = 0; k < 8; ++k) { v[k] = xr[k * 64 + lane]; ss += v[k] * v[k]; }
  ss = wred_sum(ss);
  const float r = 22.627416998f / fmaxf(sqrtf(ss), 1e-12f);
  bf16_t* yr = y + (size_t)token * 512;
#pragma unroll
  for (int k = 0; k < 8; ++k) yr[k * 64 + lane] = (bf16_t)(v[k] * r * gamma[k * 64 + lane]);
}

// ---------------- V transpose: qkv -> vT[(bf*8+h)][d][j] ----------------
__global__ __launch_bounds__(256) void st_vtrans(const bf16_t* __restrict__ qkv,
                                                 bf16_t* __restrict__ vT) {
  __shared__ float tile[32][33];
  const int jt = blockIdx.x, dt = blockIdx.y, z = blockIdx.z;
  const int bf = z >> 3, h = z & 7;
  const int tx = threadIdx.x & 31, ty = threadIdx.x >> 5;
#pragma unroll
  for (int k = 0; k < 4; ++k) {
    int j = jt * 32 + ty + k * 8;
    int d = dt * 32 + tx;
    tile[ty + k * 8][tx] = (float)qkv[((size_t)(bf * 1024 + j)) * 1536 + 1024 + h * 64 + d];
  }
  __syncthreads();
#pragma unroll
  for (int k = 0; k < 4; ++k) {
    int d = dt * 32 + ty + k * 8;
    int j = jt * 32 + tx;
    vT[((size_t)z * 64 + d) * 1024 + j] = (bf16_t)tile[tx][ty + k * 8];
  }
}

// ---------------- fused flash spatial attention ----------------
// R6: back to R2's proven structure (coalesced LDS staging, qtile-major grid)
// + double-buffered K/V prefetch (load latency leaves the critical path; one
// barrier/iter) + 52.4 KB LDS -> 3 blocks/CU (Q staging aliased over P buffer,
// P stride 64 XOR-swizzled, restricted bias table).
// R5 lesson: direct-global K-frags are 3KB-stride gathers (16 lines/instr) - bad.
__global__ __launch_bounds__(256, 3) void st_flash(
    const bf16_t* __restrict__ qkv, const bf16_t* __restrict__ vT,
    const bf16_t* __restrict__ tabb, bf16_t* __restrict__ ob) {
  __shared__ __align__(16) bf16_t ldsK[2][64 * 64];
  __shared__ __align__(16) bf16_t ldsV[2][64 * 64];
  __shared__ __align__(16) bf16_t ldsP[4 * 32 * 64];  // doubles as Q staging (16 KB)
  __shared__ __align__(16) bf16_t ldsT[2216];
  const int qtile = blockIdx.x;
  const int z = blockIdx.y;
  const int bf = z >> 3, h = z & 7;
  const int tid = threadIdx.x;
  const int lane = tid & 63, wave = tid >> 6;
  const int cl = lane & 15, g = lane >> 4;
  const size_t qkvBase = (size_t)bf * 1024 * 1536 + h * 64;
  const int eoff = (qtile * 252) & ~7;
  const bf16_t* Kp = qkv + qkvBase + 512;
  const bf16_t* Vp = vT + (size_t)z * 65536;

  // stage Q (into ldsP alias) + restricted bias table + K/V tile 0
#pragma unroll
  for (int it = 0; it < 4; ++it) {
    int s = it * 256 + tid;
    int row = s >> 3, c = s & 7;
    int cs = c ^ (row & 7);
    async16(qkv + qkvBase + (size_t)(qtile * 128 + row) * 1536 + cs * 8,
            (char*)ldsP + s * 16);
  }
#pragma unroll
  for (int it = 0; it < 2; ++it) {
    int s = it * 256 + tid;
    if (s < 277) async16(tabb + h * 4000 + eoff + s * 8, (char*)ldsT + s * 16);
  }
#pragma unroll
  for (int it = 0; it < 2; ++it) {
    int s = it * 256 + tid;
    int row = s >> 3, c = s & 7;
    int cs = c ^ (row & 7);
    async16(Kp + (size_t)row * 1536 + cs * 8, (char*)ldsK[0] + s * 16);
    async16(Vp + (size_t)row * 1024 + cs * 8, (char*)ldsV[0] + s * 16);
  }
  __syncthreads();
  // Q LDS -> registers
  bf16x8 aq[2][2];
#pragma unroll
  for (int it = 0; it < 2; ++it)
#pragma unroll
    for (int ks = 0; ks < 2; ++ks) {
      int row = wave * 32 + it * 16 + cl;
      int cs = (g + ks * 4) ^ (row & 7);
      aq[it][ks] = *(const bf16x8*)(ldsP + row * 64 + cs * 8);
    }
  __syncthreads();  // all waves consumed Q before ldsP is reused for P

  int fiB[2][4];
#pragma unroll
  for (int it = 0; it < 2; ++it)
#pragma unroll
    for (int r = 0; r < 4; ++r) {
      int i = qtile * 128 + wave * 32 + it * 16 + g * 4 + r;
      fiB[it][r] = (i >> 5) * 63 + (i & 31) + 1984 - eoff;
    }
  float lsum[2][4];
  floatx4 oacc[2][4];
#pragma unroll
  for (int it = 0; it < 2; ++it)
#pragma unroll
    for (int r = 0; r < 4; ++r) lsum[it][r] = 0.f;
#pragma unroll
  for (int it = 0; it < 2; ++it)
#pragma unroll
    for (int dt = 0; dt < 4; ++dt) oacc[it][dt] = floatx4{0.f, 0.f, 0.f, 0.f};

  bf16_t* ldsPw = ldsP + wave * (32 * 64);

#pragma unroll 2
  for (int t = 0; t < 16; ++t) {
    const int p = t & 1;
    // prefetch tile t+1 into the other buffer (drained by end-of-iter barrier,
    // by which time a full compute phase has elapsed)
    if (t < 15) {
      const int j1 = (t + 1) * 64;
#pragma unroll
      for (int it = 0; it < 2; ++it) {
        int s = it * 256 + tid;
        int row = s >> 3, c = s & 7;
        int cs = c ^ (row & 7);
        async16(Kp + (size_t)(j1 + row) * 1536 + cs * 8, (char*)ldsK[p ^ 1] + s * 16);
        async16(Vp + (size_t)row * 1024 + j1 + cs * 8, (char*)ldsV[p ^ 1] + s * 16);
      }
    }
    const int j0 = t * 64;
    // S = Q K^T
    floatx4 sacc[2][4];
#pragma unroll
    for (int it = 0; it < 2; ++it)
#pragma unroll
      for (int jt = 0; jt < 4; ++jt) sacc[it][jt] = floatx4{0.f, 0.f, 0.f, 0.f};
#pragma unroll
    for (int ks = 0; ks < 2; ++ks) {
#pragma unroll
      for (int jt = 0; jt < 4; ++jt) {
        int col = jt * 16 + cl;
        bf16x8 bk = *(const bf16x8*)(ldsK[p] + col * 64 + ((g + ks * 4) ^ (col & 7)) * 8);
#pragma unroll
        for (int it = 0; it < 2; ++it)
          sacc[it][jt] = __builtin_amdgcn_mfma_f32_16x16x32_bf16(aq[it][ks], bk, sacc[it][jt], 0, 0, 0);
      }
    }
    // bias + exp + row-sum, P -> wave-private swizzled LDS
#pragma unroll
    for (int jt = 0; jt < 4; ++jt) {
      int j = j0 + jt * 16 + cl;
      int fj = (j >> 5) * 63 + (j & 31);
      int pg = (jt * 2 + (cl >> 3));
#pragma unroll
      for (int it = 0; it < 2; ++it) {
#pragma unroll
        for (int r = 0; r < 4; ++r) {
          float e = __expf(sacc[it][jt][r] * 0.125f + (float)ldsT[fiB[it][r] - fj]);
          lsum[it][r] += e;
          int prow = it * 16 + g * 4 + r;
          ldsPw[prow * 64 + (pg ^ (prow & 7)) * 8 + (cl & 7)] = (bf16_t)e;
        }
      }
    }
    // O += P V  (wave-private P; lgkmcnt orders write->read, no barrier)
#pragma unroll
    for (int ks = 0; ks < 2; ++ks) {
      bf16x8 ap[2];
#pragma unroll
      for (int it = 0; it < 2; ++it)
        ap[it] = *(const bf16x8*)(ldsPw + (it * 16 + cl) * 64 + ((g + ks * 4) ^ (cl & 7)) * 8);
#pragma unroll
      for (int dt = 0; dt < 4; ++dt) {
        int d = dt * 16 + cl;
        bf16x8 bv = *(const bf16x8*)(ldsV[p] + d * 64 + ((g + ks * 4) ^ (d & 7)) * 8);
#pragma unroll
        for (int it = 0; it < 2; ++it)
          oacc[it][dt] = __builtin_amdgcn_mfma_f32_16x16x32_bf16(ap[it], bv, oacc[it][dt], 0, 0, 0);
      }
    }
    __syncthreads();
  }
  // normalize + write
#pragma unroll
  for (int it = 0; it < 2; ++it)
#pragma unroll
    for (int r = 0; r < 4; ++r) {
#pragma unroll
      for (int x = 1; x < 16; x <<= 1) lsum[it][r] += __shfl_xor(lsum[it][r], x);
      lsum[it][r] = 1.f / lsum[it][r];
    }
#pragma unroll
  for (int it = 0; it < 2; ++it) {
#pragma unroll
    for (int r = 0; r < 4; ++r) {
      int i = qtile * 128 + wave * 32 + it * 16 + g * 4 + r;
      size_t base = ((size_t)bf * 1024 + i) * 512 + h * 64;
#pragma unroll
      for (int dt = 0; dt < 4; ++dt)
        ob[base + dt * 16 + cl] = (bf16_t)(oacc[it][dt][r] * lsum[it][r]);
    }
  }
}

// ---------------- temporal attention (seq=8), log-transpose reduce ----------------
__global__ __launch_bounds__(256) void st_tattn2(const bf16_t* __restrict__ qkv,
                                                 const float* __restrict__ tabf,
                                                 bf16_t* __restrict__ o) {
  const int wg = blockIdx.x * 4 + (threadIdx.x >> 6);
  const int bhw = wg >> 3, head = wg & 7;
  const int lane = threadIdx.x & 63;
  const size_t base = (size_t)bhw * 8 * 1536 + head * 64 + lane;
  float q[8], k[8], v[8];
#pragma unroll
  for (int f = 0; f < 8; ++f) {
    q[f] = (float)qkv[base + (size_t)f * 1536];
    k[f] = (float)qkv[base + (size_t)f * 1536 + 512];
    v[f] = (float)qkv[base + (size_t)f * 1536 + 1024];
  }
  float p[64];
#pragma unroll
  for (int i = 0; i < 8; ++i)
#pragma unroll
    for (int j = 0; j < 8; ++j) p[i * 8 + j] = q[i] * k[j];
#pragma unroll
  for (int st = 32; st >= 1; st >>= 1) {
    const bool hi = (lane & st) != 0;
#pragma unroll
    for (int m = 0; m < st; ++m) {
      float give = hi ? p[m] : p[m + st];
      float keep = hi ? p[m + st] : p[m];
      p[m] = keep + __shfl_xor(give, st);
    }
  }
  const int i = lane >> 3, j = lane & 7;
  float e = __expf(p[0] * 0.125f + tabf[head * 15 + i - j + 7]);
  float sm = e;
  sm += __shfl_xor(sm, 1);
  sm += __shfl_xor(sm, 2);
  sm += __shfl_xor(sm, 4);
  const float prob = e / sm;
  float acc[8];
#pragma unroll
  for (int ii = 0; ii < 8; ++ii) acc[ii] = 0.f;
#pragma unroll
  for (int ii = 0; ii < 8; ++ii)
#pragma unroll
    for (int jj = 0; jj < 8; ++jj)
      acc[ii] += __shfl(prob, ii * 8 + jj) * v[jj];
#pragma unroll
  for (int ii = 0; ii < 8; ++ii)
    o[(size_t)(bhw * 8 + ii) * 512 + head * 64 + lane] = (bf16_t)acc[ii];
}

// ---------------- permute (b,f,hw,c) <-> (b,hw,f,c), optional fused bf16 cast ----------------
__global__ void st_permute(const float* __restrict__ in, float* __restrict__ out, int dir,
                           bf16_t* __restrict__ out2) {
  size_t idx = (size_t)blockIdx.x * 256 + threadIdx.x;
  int c = (int)(idx & 511);
  size_t r = idx >> 9;
  size_t src;
  if (dir == 0) {
    int f = (int)(r & 7);
    int hw = (int)((r >> 3) & 1023);
    int b = (int)(r >> 13);
    src = ((((size_t)b * 8 + f) * 1024 + hw) << 9) + c;
  } else {
    int hw = (int)(r & 1023);
    int f = (int)((r >> 10) & 7);
    int b = (int)(r >> 13);
    src = ((((size_t)b * 1024 + hw) * 8 + f) << 9) + c;
  }
  float v = in[src];
  out[idx] = v;
  if (out2) out2[idx] = (bf16_t)v;
}

// ---------------- GeGLU + temporal shift + RMS -> yn bf16 (K padded to 1376) ----------------
__global__ __launch_bounds__(256) void st_glu(const bf16_t* __restrict__ hdn,
                                              const float* __restrict__ gamma,
                                              bf16_t* __restrict__ yn) {
  const int t = blockIdx.x;
  const int tid = threadIdx.x;
  const int f = (t >> 10) & 7;
  float y[6];
  float ss = 0.f;
#pragma unroll
  for (int kk = 0; kk < 6; ++kk) {
    int c = kk * 256 + tid;
    float yv = 0.f;
    if (c < 1365) {
      long src = t;
      bool valid = true;
      if (c >= 683) { if (f == 0) valid = false; else src = t - 1024; }
      if (valid) {
        float av = (float)hdn[src * 2730 + c];
        float gv = (float)hdn[src * 2730 + 1365 + c];
        yv = av * 0.5f * gv * (1.f + erff(gv * 0.70710678f));
      }
    }
    y[kk] = yv;
    ss += yv * yv;
  }
  __shared__ float red[4];
  ss = wred_sum(ss);
  if ((tid & 63) == 0) red[tid >> 6] = ss;
  __syncthreads();
  ss = red[0] + red[1] + red[2] + red[3];
  const float r = sqrtf(1365.f) / fmaxf(sqrtf(ss), 1e-12f);
#pragma unroll
  for (int kk = 0; kk < 6; ++kk) {
    int c = kk * 256 + tid;
    if (c < 1365) yn[(size_t)t * 1376 + c] = (bf16_t)(y[kk] * r * gamma[c]);
  }
  if (tid < 11) yn[(size_t)t * 1376 + 1365 + tid] = (bf16_t)0.f;
}

// ---------------- launcher ----------------
extern "C" void kernel_launch(void* const* d_in, const int* in_sizes, int n_in,
                              void* d_out, int out_size, void* d_ws, size_t ws_size,
                              hipStream_t stream) {
  const float* x        = (const float*)d_in[0];
  const float* sa_gamma = (const float*)d_in[1];
  const float* sa_wq    = (const float*)d_in[2];
  const float* sa_wkv   = (const float*)d_in[3];
  const float* sa_wo    = (const float*)d_in[4];
  const float* ta_gamma = (const float*)d_in[5];
  const float* ta_wq    = (const float*)d_in[6];
  const float* ta_wkv   = (const float*)d_in[7];
  const float* ta_wo    = (const float*)d_in[8];
  const float* sp_w1 = (const float*)d_in[9];
  const float* sp_b1 = (const float*)d_in[10];
  const float* sp_w2 = (const float*)d_in[11];
  const float* sp_b2 = (const float*)d_in[12];
  const float* sp_w3 = (const float*)d_in[13];
  const float* sp_b3 = (const float*)d_in[14];
  const float* tp_w1 = (const float*)d_in[15];
  const float* tp_b1 = (const float*)d_in[16];
  const float* tp_w2 = (const float*)d_in[17];
  const float* tp_b2 = (const float*)d_in[18];
  const float* tp_w3 = (const float*)d_in[19];
  const float* tp_b3 = (const float*)d_in[20];
  const float* ff_win   = (const float*)d_in[21];
  const float* ff_gamma = (const float*)d_in[22];
  const float* ff_wout  = (const float*)d_in[23];
  float* outp = (float*)d_out;

  char* ws = (char*)d_ws;
  size_t off = 0;
  auto alloc = [&](size_t bytes) -> char* {
    char* p = ws + off;
    off += (bytes + 255) & ~(size_t)255;
    return p;
  };
  const long T = 16384;
  float*  xs  = (float*)alloc((size_t)T * 512 * 4);    // residual stream
  bf16_t* xn  = (bf16_t*)alloc((size_t)T * 512 * 2);   // normed input
  char*   R2  = alloc((size_t)T * 1536 * 2);           // qkv | FF: hdn (spans R2+R3)
  char*   R3  = alloc((size_t)T * 1536 * 2);           // vT+ob | xt+ob | hdn tail
  bf16_t* ynb = (bf16_t*)alloc((size_t)T * 1376 * 2);
  bf16_t* wqkvT_sa = (bf16_t*)alloc(1536ULL * 512 * 2);
  bf16_t* woT_sa   = (bf16_t*)alloc(512ULL * 512 * 2);
  bf16_t* wqkvT_ta = (bf16_t*)alloc(1536ULL * 512 * 2);
  bf16_t* woT_ta   = (bf16_t*)alloc(512ULL * 512 * 2);
  bf16_t* winT  = (bf16_t*)alloc(2730ULL * 512 * 2);
  bf16_t* woutT = (bf16_t*)alloc(512ULL * 1376 * 2);
  bf16_t* tabb  = (bf16_t*)alloc(8 * 4000 * 2);
  float*  tabf  = (float*)alloc(8 * 15 * 4);

  bf16_t* qkv  = (bf16_t*)R2;
  bf16_t* hdn  = (bf16_t*)R2;                       // FF: 16384x2730 bf16 = 85.3MB <= R2+R3 (96MB)
  bf16_t* vT   = (bf16_t*)R3;                       // spatial
  bf16_t* ob_s = (bf16_t*)(R3 + (size_t)T * 512 * 2);
  float*  xt   = (float*)R3;                        // temporal
  bf16_t* ob_t = (bf16_t*)(R3 + (size_t)T * 512 * 4);

  // 1) input: per b transpose (512 x 8192) -> (8192 x 512)
  st_transpose2d<<<dim3(256, 16, 2), 256, 0, stream>>>(x, xs, 512, 8192,
                                                       (long long)512 * 8192, (long long)512 * 8192);
  // 2) weight transposes
  auto wt = [&](const float* src, bf16_t* dst, int K, int Kpad, int N, int srcld, int coloff) {
    long tot = (long)N * Kpad;
    st_wtrans<<<dim3((tot + 255) / 256), 256, 0, stream>>>(src, dst, K, Kpad, N, srcld, coloff, tot);
  };
  wt(sa_wq, wqkvT_sa, 512, 512, 512, 512, 0);
  wt(sa_wkv, wqkvT_sa + 512 * 512, 512, 512, 1024, 1024, 0);
  wt(sa_wo, woT_sa, 512, 512, 512, 512, 0);
  wt(ta_wq, wqkvT_ta, 512, 512, 512, 512, 0);
  wt(ta_wkv, wqkvT_ta + 512 * 512, 512, 512, 1024, 1024, 0);
  wt(ta_wo, woT_ta, 512, 512, 512, 512, 0);
  wt(ff_win, winT, 512, 512, 2730, 2730, 0);
  wt(ff_wout, woutT, 1365, 1376, 512, 512, 0);
  // 3) CPB tables
  st_cpb<<<dim3(3969), 256, 0, stream>>>(sp_w1, sp_b1, sp_w2, sp_b2, sp_w3, sp_b3, tabb, tabf, 1);
  st_cpb<<<dim3(15), 256, 0, stream>>>(tp_w1, tp_b1, tp_w2, tp_b2, tp_w3, tp_b3, tabb, tabf, 0);

  // ---- spatial attention ----
  st_rmsnorm<<<dim3(4096), 256, 0, stream>>>(xs, sa_gamma, xn);
  st_gemm<true, false><<<dim3(128, 12, 1), 256, 0, stream>>>(
      xn, wqkvT_sa, (void*)qkv, nullptr, 16384, 1536, 512, 512, 512, 1536, 1, 0, 0, 0, 0, 0, 0);
  st_vtrans<<<dim3(32, 2, 128), 256, 0, stream>>>(qkv, vT);
  st_flash<<<dim3(8, 128), 256, 0, stream>>>(qkv, vT, tabb, ob_s);
  st_gemm<false, true><<<dim3(128, 4, 1), 256, 0, stream>>>(
      ob_s, woT_sa, (void*)xs, xs, 16384, 512, 512, 512, 512, 512, 1, 0, 0, 0, 0, 0, 0);

  // ---- temporal attention ----
  st_permute<<<dim3(32768), 256, 0, stream>>>(xs, xt, 0, nullptr);
  st_rmsnorm<<<dim3(4096), 256, 0, stream>>>(xt, ta_gamma, xn);
  st_gemm<true, false><<<dim3(128, 12, 1), 256, 0, stream>>>(
      xn, wqkvT_ta, (void*)qkv, nullptr, 16384, 1536, 512, 512, 512, 1536, 1, 0, 0, 0, 0, 0, 0);
  st_tattn2<<<dim3(4096), 256, 0, stream>>>(qkv, tabf, ob_t);
  st_gemm<false, true><<<dim3(128, 4, 1), 256, 0, stream>>>(
      ob_t, woT_ta, (void*)xt, xt, 16384, 512, 512, 512, 512, 512, 1, 0, 0, 0, 0, 0, 0);
  st_permute<<<dim3(32768), 256, 0, stream>>>(xt, xs, 1, xn);  // fused residual copy + cast

  // ---- feed-forward ----
  st_gemm<true, false><<<dim3(128, 22, 1), 256, 0, stream>>>(
      xn, winT, (void*)hdn, nullptr, 16384, 2730, 512, 512, 512, 2730, 1, 0, 0, 0, 0, 0, 0);
  st_glu<<<dim3(16384), 256, 0, stream>>>(hdn, ff_gamma, ynb);
  st_gemm<false, true><<<dim3(128, 4, 1), 256, 0, stream>>>(
      ynb, woutT, (void*)xs, xs, 16384, 512, 1376, 1376, 1376, 512, 1, 0, 0, 0, 0, 0, 0);

  // ---- output: per b transpose (8192 x 512) -> (512 x 8192) ----
  st_transpose2d<<<dim3(16, 256, 2), 256, 0, stream>>>(xs, outp, 8192, 512,
                                                       (long long)8192 * 512, (long long)8192 * 512);
}

// Round 7
// 704.501 us; speedup vs baseline: 1.2225x; 1.0556x over previous
//
#include <hip/hip_runtime.h>
#include <cstdint>
#include <cstddef>

typedef __bf16 bf16_t;
typedef __bf16 bf16x8 __attribute__((ext_vector_type(8)));
typedef __bf16 bf16x4 __attribute__((ext_vector_type(4)));
typedef float floatx4 __attribute__((ext_vector_type(4)));

// ---------------- helpers ----------------
__device__ __forceinline__ float wred_sum(float v) {
#pragma unroll
  for (int off = 32; off > 0; off >>= 1) v += __shfl_xor(v, off);
  return v;
}
__device__ __forceinline__ void async16(const void* g, void* l) {
  __builtin_amdgcn_global_load_lds((const __attribute__((address_space(1))) void*)g,
                                   (__attribute__((address_space(3))) void*)l, 16, 0, 0);
}

// ---------------- generic batched bf16 GEMM (m97 structure) ----------------
// MODE: 0 f32 out | 1 bf16 out | 2 f32 out + resid |
//       3 resid + spatial->temporal permuted f32 write |
//       4 resid + temporal->spatial permuted f32 write + bf16 dual write |
//       5 GeGLU epilogue (interleaved a/gate cols) -> bf16 y [M x 1365]
template <int MODE>
__global__ __launch_bounds__(256) void st_gemm(
    const bf16_t* __restrict__ A, const bf16_t* __restrict__ B, void* Cp, void* Cp2,
    const float* Res, int M, int N, int K, int lda, int ldb, int ldc, int nb1,
    long long sa1, long long sa2, long long sb1, long long sb2,
    long long sc1, long long sc2) {
  __shared__ bf16_t sA[128 * 32];
  __shared__ bf16_t sB[128 * 32];
  const int z = blockIdx.z;
  const int z1 = z % nb1, z2 = z / nb1;
  A += z1 * sa1 + z2 * sa2;
  B += z1 * sb1 + z2 * sb2;
  const long long coff = z1 * sc1 + z2 * sc2;
  const int tid = threadIdx.x;
  const int bm = blockIdx.x, bn = blockIdx.y;
  const int lane = tid & 63;
  const int wave = tid >> 6;
  const int wm = (wave >> 1) * 64, wn = (wave & 1) * 64;
  const int rowf = lane & 15, kq = (lane >> 4) * 8;

  floatx4 acc[4][4];
#pragma unroll
  for (int i = 0; i < 4; ++i)
#pragma unroll
    for (int j = 0; j < 4; ++j) acc[i][j] = floatx4{0.f, 0.f, 0.f, 0.f};

  for (int kt = 0; kt < K; kt += 32) {
#pragma unroll
    for (int it = 0; it < 2; ++it) {
      int slot = it * 256 + tid;
      int mi = slot >> 2, kc = slot & 3;
      int ar = bm * 128 + mi; if (ar > M - 1) ar = M - 1;
      int br = bn * 128 + mi; if (br > N - 1) br = N - 1;
      async16(A + (size_t)ar * lda + kt + kc * 8, (char*)sA + slot * 16);
      async16(B + (size_t)br * ldb + kt + kc * 8, (char*)sB + slot * 16);
    }
    __syncthreads();
    bf16x8 af[4], bv[4];
#pragma unroll
    for (int i = 0; i < 4; ++i) {
      af[i] = *(const bf16x8*)(sA + (wm + i * 16 + rowf) * 32 + kq);
      bv[i] = *(const bf16x8*)(sB + (wn + i * 16 + rowf) * 32 + kq);
    }
#pragma unroll
    for (int i = 0; i < 4; ++i)
#pragma unroll
      for (int j = 0; j < 4; ++j)
        acc[i][j] = __builtin_amdgcn_mfma_f32_16x16x32_bf16(af[i], bv[j], acc[i][j], 0, 0, 0);
    __syncthreads();
  }

  const int cl = lane & 15;
  const int rowBase = bm * 128 + wm + (lane >> 4) * 4;
  if (MODE == 5) {
    // GeGLU: col pairs (jt even = a-tile, jt odd = gate-tile for the same c-group)
    bf16_t* yb = (bf16_t*)Cp;
    const int cg0 = ((bn * 128 + wn) >> 5) * 16;
#pragma unroll
    for (int i = 0; i < 4; ++i) {
#pragma unroll
      for (int p = 0; p < 2; ++p) {
        int c = cg0 + p * 16 + cl;
        if (c >= 1365) continue;
#pragma unroll
        for (int r = 0; r < 4; ++r) {
          int row = rowBase + i * 16 + r;
          if (row >= M) continue;
          float a = acc[i][2 * p][r];
          float gt = acc[i][2 * p + 1][r];
          float y = a * 0.5f * gt * (1.f + erff(gt * 0.70710678f));
          yb[(size_t)row * ldc + c] = (bf16_t)y;
        }
      }
    }
    return;
  }
  const int colBase = bn * 128 + wn + cl;
#pragma unroll
  for (int i = 0; i < 4; ++i) {
#pragma unroll
    for (int j = 0; j < 4; ++j) {
      int col = colBase + j * 16;
      if (col >= N) continue;
#pragma unroll
      for (int r = 0; r < 4; ++r) {
        int row = rowBase + i * 16 + r;
        if (row >= M) continue;
        long long inidx = coff + (long long)row * ldc + col;
        float v = acc[i][j][r];
        if (MODE >= 2) v += Res[inidx];
        if (MODE == 0) { ((float*)Cp)[inidx] = v; }
        else if (MODE == 1) { ((bf16_t*)Cp)[inidx] = (bf16_t)v; }
        else if (MODE == 2) { ((float*)Cp)[inidx] = v; }
        else if (MODE == 3) {
          int orow = (row & ~8191) | ((row & 1023) << 3) | ((row >> 10) & 7);
          ((float*)Cp)[coff + (long long)orow * ldc + col] = v;
        } else if (MODE == 4) {
          int orow = (row & ~8191) | ((row & 7) << 10) | ((row >> 3) & 1023);
          long long oidx = coff + (long long)orow * ldc + col;
          ((float*)Cp)[oidx] = v;
          ((bf16_t*)Cp2)[oidx] = (bf16_t)v;
        }
      }
    }
  }
}

// ---------------- tiled fp32 transpose (R x C) -> (C x R), batched ----------------
__global__ __launch_bounds__(256) void st_transpose2d(
    const float* __restrict__ in, float* __restrict__ out, int R, int Cc,
    long long inb, long long outb) {
  __shared__ float tile[32][33];
  const int ct = blockIdx.x, rt = blockIdx.y, b = blockIdx.z;
  in += (long long)b * inb;
  out += (long long)b * outb;
  const int tx = threadIdx.x & 31, ty = threadIdx.x >> 5;
#pragma unroll
  for (int k = 0; k < 4; ++k) {
    int r = rt * 32 + ty + k * 8;
    int c = ct * 32 + tx;
    tile[ty + k * 8][tx] = in[(size_t)r * Cc + c];
  }
  __syncthreads();
#pragma unroll
  for (int k = 0; k < 4; ++k) {
    int c = ct * 32 + ty + k * 8;
    int r = rt * 32 + tx;
    out[(size_t)c * R + r] = tile[tx][ty + k * 8];
  }
}

// ---------------- weight transpose fp32 (K x N) -> bf16 (N x Kpad) ----------------
__global__ void st_wtrans(const float* __restrict__ src, bf16_t* __restrict__ dst,
                          int K, int Kpad, int N, int srcld, int coloff, long total) {
  long idx = (long)blockIdx.x * 256 + threadIdx.x;
  if (idx >= total) return;
  int kp = (int)(idx % Kpad);
  int n = (int)(idx / Kpad);
  float v = (kp < K) ? src[(size_t)kp * srcld + coloff + n] : 0.f;
  dst[idx] = (bf16_t)v;
}

// winT GeGLU-interleave: dst row n (0..2751): block=n>>5, w=n&31;
// c = block*16 + (w&15); a if w<16 else gate (srccol += 1365); pad rows -> 0
__global__ void st_wtrans_geglu(const float* __restrict__ src, bf16_t* __restrict__ dst,
                                long total) {
  long idx = (long)blockIdx.x * 256 + threadIdx.x;
  if (idx >= total) return;
  int kp = (int)(idx & 511);
  int n = (int)(idx >> 9);
  int c = ((n >> 5) << 4) + (n & 15);
  float v = 0.f;
  if (c < 1365) {
    int srccol = c + (((n >> 4) & 1) ? 1365 : 0);
    v = src[(size_t)kp * 2730 + srccol];
  }
  dst[idx] = (bf16_t)v;
}

// ---------------- CPB MLP tables (2d table pre-scaled by log2e for exp2) ----------------
__global__ __launch_bounds__(256) void st_cpb(
    const float* __restrict__ w1, const float* __restrict__ b1,
    const float* __restrict__ w2, const float* __restrict__ b2,
    const float* __restrict__ w3, const float* __restrict__ b3,
    bf16_t* __restrict__ tab2d, float* __restrict__ tab1d, int two_d) {
  const int pos = blockIdx.x, t = threadIdx.x;
  float r0, r1 = 0.f;
  if (two_d) { r0 = (float)(pos / 63 - 31); r1 = (float)(pos % 63 - 31); }
  else { r0 = (float)(pos - 7); }
  __shared__ float sh[256];
  float h = r0 * w1[t] + (two_d ? r1 * w1[256 + t] : 0.f) + b1[t];
  h = h / (1.f + expf(-h));
  sh[t] = h;
  __syncthreads();
  float h2 = b2[t];
  for (int j = 0; j < 256; ++j) h2 += sh[j] * w2[j * 256 + t];
  h2 = h2 / (1.f + expf(-h2));
  __syncthreads();
  sh[t] = h2;
  __syncthreads();
  if (t < 8) {
    float o = b3[t];
    for (int j = 0; j < 256; ++j) o += sh[j] * w3[j * 8 + t];
    if (two_d) tab2d[t * 4000 + pos] = (bf16_t)(o * 1.4426950408889634f);
    else tab1d[t * 15 + pos] = o;
  }
}

// ---------------- RMS norm -> bf16 ----------------
__global__ __launch_bounds__(256) void st_rmsnorm(const float* __restrict__ x,
                                                  const float* __restrict__ gamma,
                                                  bf16_t* __restrict__ y) {
  const int token = blockIdx.x * 4 + (threadIdx.x >> 6);
  const int lane = threadIdx.x & 63;
  const float* xr = x + (size_t)token * 512;
  float v[8];
  float ss = 0.f;
#pragma unroll
  for (int k = 0; k < 8; ++k) { v[k] = xr[k * 64 + lane]; ss += v[k] * v[k]; }
  ss = wred_sum(ss);
  const float r = 22.627416998f / fmaxf(sqrtf(ss), 1e-12f);
  bf16_t* yr = y + (size_t)token * 512;
#pragma unroll
  for (int k = 0; k < 8; ++k) yr[k * 64 + lane] = (bf16_t)(v[k] * r * gamma[k * 64 + lane]);
}

// ---------------- V transpose: qkv -> vT[(bf*8+h)][d][j] ----------------
__global__ __launch_bounds__(256) void st_vtrans(const bf16_t* __restrict__ qkv,
                                                 bf16_t* __restrict__ vT) {
  __shared__ float tile[32][33];
  const int jt = blockIdx.x, dt = blockIdx.y, z = blockIdx.z;
  const int bf = z >> 3, h = z & 7;
  const int tx = threadIdx.x & 31, ty = threadIdx.x >> 5;
#pragma unroll
  for (int k = 0; k < 4; ++k) {
    int j = jt * 32 + ty + k * 8;
    int d = dt * 32 + tx;
    tile[ty + k * 8][tx] = (float)qkv[((size_t)(bf * 1024 + j)) * 1536 + 1024 + h * 64 + d];
  }
  __syncthreads();
#pragma unroll
  for (int k = 0; k < 4; ++k) {
    int d = dt * 32 + ty + k * 8;
    int j = jt * 32 + tx;
    vT[((size_t)z * 64 + d) * 1024 + j] = (bf16_t)tile[tx][ty + k * 8];
  }
}

// ---------------- fused flash spatial attention (R7: S^T formulation) ----------------
// Computes S^T = K Q^T so each lane's C-fragment has FIXED query i=cl and 4
// CONSECUTIVE j per (jt) -> P written with 8 ds_write_b64 (was 32 ds_write_b16),
// PV as O^T = V^T P^T, per-lane lsum (2 end shuffles), dwordx2 output stores.
// exp via exp2 with log2e folded into the bias table. Double-buffered K/V,
// 1 barrier/iter, 52.4 KB LDS, 3 blk/CU (as R6).
__global__ __launch_bounds__(256, 3) void st_flash(
    const bf16_t* __restrict__ qkv, const bf16_t* __restrict__ vT,
    const bf16_t* __restrict__ tabb, bf16_t* __restrict__ ob) {
  __shared__ __align__(16) bf16_t ldsK[2][64 * 64];
  __shared__ __align__(16) bf16_t ldsV[2][64 * 64];
  __shared__ __align__(16) bf16_t ldsP[4 * 32 * 64];  // doubles as Q staging (16 KB)
  __shared__ __align__(16) bf16_t ldsT[2216];
  const int qtile = blockIdx.x;
  const int z = blockIdx.y;
  const int bf = z >> 3, h = z & 7;
  const int tid = threadIdx.x;
  const int lane = tid & 63, wave = tid >> 6;
  const int cl = lane & 15, g = lane >> 4;
  const size_t qkvBase = (size_t)bf * 1024 * 1536 + h * 64;
  const int eoff = (qtile * 252) & ~7;
  const bf16_t* Kp = qkv + qkvBase + 512;
  const bf16_t* Vp = vT + (size_t)z * 65536;

  // stage Q (into ldsP alias) + restricted bias table + K/V tile 0
#pragma unroll
  for (int it = 0; it < 4; ++it) {
    int s = it * 256 + tid;
    int row = s >> 3, c = s & 7;
    int cs = c ^ (row & 7);
    async16(qkv + qkvBase + (size_t)(qtile * 128 + row) * 1536 + cs * 8,
            (char*)ldsP + s * 16);
  }
#pragma unroll
  for (int it = 0; it < 2; ++it) {
    int s = it * 256 + tid;
    if (s < 277) async16(tabb + h * 4000 + eoff + s * 8, (char*)ldsT + s * 16);
  }
#pragma unroll
  for (int it = 0; it < 2; ++it) {
    int s = it * 256 + tid;
    int row = s >> 3, c = s & 7;
    int cs = c ^ (row & 7);
    async16(Kp + (size_t)row * 1536 + cs * 8, (char*)ldsK[0] + s * 16);
    async16(Vp + (size_t)row * 1024 + cs * 8, (char*)ldsV[0] + s * 16);
  }
  __syncthreads();
  // Q LDS -> registers (B-operand frags: lane holds row i=cl(+16it), 8 d's)
  bf16x8 aq[2][2];
#pragma unroll
  for (int it = 0; it < 2; ++it)
#pragma unroll
    for (int ks = 0; ks < 2; ++ks) {
      int row = wave * 32 + it * 16 + cl;
      int cs = (g + ks * 4) ^ (row & 7);
      aq[it][ks] = *(const bf16x8*)(ldsP + row * 64 + cs * 8);
    }
  __syncthreads();  // all waves consumed Q before ldsP reused for P

  int fiB[2];
#pragma unroll
  for (int it = 0; it < 2; ++it) {
    int i = qtile * 128 + wave * 32 + it * 16 + cl;
    fiB[it] = (i >> 5) * 63 + (i & 31) + 1984 - eoff;
  }
  float lsum[2] = {0.f, 0.f};
  floatx4 oacc[4][2];
#pragma unroll
  for (int dt = 0; dt < 4; ++dt)
#pragma unroll
    for (int it = 0; it < 2; ++it) oacc[dt][it] = floatx4{0.f, 0.f, 0.f, 0.f};

  bf16_t* ldsPw = ldsP + wave * (32 * 64);
  const float SC = 0.18033688011112042f;  // 0.125 * log2(e)

#pragma unroll 2
  for (int t = 0; t < 16; ++t) {
    const int p = t & 1;
    if (t < 15) {
      const int j1 = (t + 1) * 64;
#pragma unroll
      for (int it = 0; it < 2; ++it) {
        int s = it * 256 + tid;
        int row = s >> 3, c = s & 7;
        int cs = c ^ (row & 7);
        async16(Kp + (size_t)(j1 + row) * 1536 + cs * 8, (char*)ldsK[p ^ 1] + s * 16);
        async16(Vp + (size_t)row * 1024 + j1 + cs * 8, (char*)ldsV[p ^ 1] + s * 16);
      }
    }
    const int j0 = t * 64;
    // S^T = K Q^T : C[j][i], lane holds (j = g*4+r, i = cl)
    floatx4 sacc[4][2];
#pragma unroll
    for (int jt = 0; jt < 4; ++jt)
#pragma unroll
      for (int it = 0; it < 2; ++it) sacc[jt][it] = floatx4{0.f, 0.f, 0.f, 0.f};
#pragma unroll
    for (int ks = 0; ks < 2; ++ks) {
#pragma unroll
      for (int jt = 0; jt < 4; ++jt) {
        int row = jt * 16 + cl;
        bf16x8 kf = *(const bf16x8*)(ldsK[p] + row * 64 + (((ks * 4 + g) ^ (row & 7))) * 8);
#pragma unroll
        for (int it = 0; it < 2; ++it)
          sacc[jt][it] = __builtin_amdgcn_mfma_f32_16x16x32_bf16(kf, aq[it][ks], sacc[jt][it], 0, 0, 0);
      }
    }
    // bias + exp2 + per-lane row-sum; P -> wave-private LDS as b64 (4 consecutive j)
#pragma unroll
    for (int jt = 0; jt < 4; ++jt) {
      int jb = j0 + jt * 16 + g * 4;
      int fjb = (jb >> 5) * 63 + (jb & 31);
      int gg = jt * 2 + (g >> 1);
#pragma unroll
      for (int it = 0; it < 2; ++it) {
        int idx0 = fiB[it] - fjb;
        float e0 = __builtin_exp2f(sacc[jt][it][0] * SC + (float)ldsT[idx0]);
        float e1 = __builtin_exp2f(sacc[jt][it][1] * SC + (float)ldsT[idx0 - 1]);
        float e2 = __builtin_exp2f(sacc[jt][it][2] * SC + (float)ldsT[idx0 - 2]);
        float e3 = __builtin_exp2f(sacc[jt][it][3] * SC + (float)ldsT[idx0 - 3]);
        lsum[it] += (e0 + e1) + (e2 + e3);
        bf16x4 pv = {(bf16_t)e0, (bf16_t)e1, (bf16_t)e2, (bf16_t)e3};
        int prow = it * 16 + cl;
        *(bf16x4*)((char*)ldsPw + prow * 128 + ((gg ^ (cl & 7)) * 16 + (g & 1) * 8)) = pv;
      }
    }
    // O^T += V^T P^T : C[d][i]
#pragma unroll
    for (int ks = 0; ks < 2; ++ks) {
      bf16x8 pB[2];
#pragma unroll
      for (int it = 0; it < 2; ++it)
        pB[it] = *(const bf16x8*)((char*)ldsPw + (it * 16 + cl) * 128 +
                                  (((ks * 4 + g) ^ (cl & 7)) * 16));
#pragma unroll
      for (int dt = 0; dt < 4; ++dt) {
        int row = dt * 16 + cl;
        bf16x8 vf = *(const bf16x8*)(ldsV[p] + row * 64 + (((ks * 4 + g) ^ (row & 7))) * 8);
#pragma unroll
        for (int it = 0; it < 2; ++it)
          oacc[dt][it] = __builtin_amdgcn_mfma_f32_16x16x32_bf16(vf, pB[it], oacc[dt][it], 0, 0, 0);
      }
    }
    __syncthreads();
  }
  // reduce lsum across quads; normalize + packed store (4 consecutive d)
  float inv[2];
#pragma unroll
  for (int it = 0; it < 2; ++it) {
    float s = lsum[it];
    s += __shfl_xor(s, 16);
    s += __shfl_xor(s, 32);
    inv[it] = 1.f / s;
  }
#pragma unroll
  for (int it = 0; it < 2; ++it) {
    int i = qtile * 128 + wave * 32 + it * 16 + cl;
    size_t base = ((size_t)bf * 1024 + i) * 512 + h * 64 + g * 4;
#pragma unroll
    for (int dt = 0; dt < 4; ++dt) {
      bf16x4 ov = {(bf16_t)(oacc[dt][it][0] * inv[it]), (bf16_t)(oacc[dt][it][1] * inv[it]),
                   (bf16_t)(oacc[dt][it][2] * inv[it]), (bf16_t)(oacc[dt][it][3] * inv[it])};
      *(bf16x4*)(ob + base + dt * 16) = ov;
    }
  }
}

// ---------------- temporal attention (seq=8), log-transpose reduce ----------------
__global__ __launch_bounds__(256) void st_tattn2(const bf16_t* __restrict__ qkv,
                                                 const float* __restrict__ tabf,
                                                 bf16_t* __restrict__ o) {
  const int wg = blockIdx.x * 4 + (threadIdx.x >> 6);
  const int bhw = wg >> 3, head = wg & 7;
  const int lane = threadIdx.x & 63;
  const size_t base = (size_t)bhw * 8 * 1536 + head * 64 + lane;
  float q[8], k[8], v[8];
#pragma unroll
  for (int f = 0; f < 8; ++f) {
    q[f] = (float)qkv[base + (size_t)f * 1536];
    k[f] = (float)qkv[base + (size_t)f * 1536 + 512];
    v[f] = (float)qkv[base + (size_t)f * 1536 + 1024];
  }
  float p[64];
#pragma unroll
  for (int i = 0; i < 8; ++i)
#pragma unroll
    for (int j = 0; j < 8; ++j) p[i * 8 + j] = q[i] * k[j];
#pragma unroll
  for (int st = 32; st >= 1; st >>= 1) {
    const bool hi = (lane & st) != 0;
#pragma unroll
    for (int m = 0; m < st; ++m) {
      float give = hi ? p[m] : p[m + st];
      float keep = hi ? p[m + st] : p[m];
      p[m] = keep + __shfl_xor(give, st);
    }
  }
  const int i = lane >> 3, j = lane & 7;
  float e = __expf(p[0] * 0.125f + tabf[head * 15 + i - j + 7]);
  float sm = e;
  sm += __shfl_xor(sm, 1);
  sm += __shfl_xor(sm, 2);
  sm += __shfl_xor(sm, 4);
  const float prob = e / sm;
  float acc[8];
#pragma unroll
  for (int ii = 0; ii < 8; ++ii) acc[ii] = 0.f;
#pragma unroll
  for (int ii = 0; ii < 8; ++ii)
#pragma unroll
    for (int jj = 0; jj < 8; ++jj)
      acc[ii] += __shfl(prob, ii * 8 + jj) * v[jj];
#pragma unroll
  for (int ii = 0; ii < 8; ++ii)
    o[(size_t)(bhw * 8 + ii) * 512 + head * 64 + lane] = (bf16_t)acc[ii];
}

// ---------------- temporal shift + RMS on pre-activated y -> ynb (K padded 1376) ----------------
__global__ __launch_bounds__(256) void st_glu(const bf16_t* __restrict__ y,
                                              const float* __restrict__ gamma,
                                              bf16_t* __restrict__ yn) {
  const int t = blockIdx.x;
  const int tid = threadIdx.x;
  const int f = (t >> 10) & 7;
  float yv[6];
  float ss = 0.f;
#pragma unroll
  for (int kk = 0; kk < 6; ++kk) {
    int c = kk * 256 + tid;
    float v = 0.f;
    if (c < 1365) {
      long src = t;
      bool valid = true;
      if (c >= 683) { if (f == 0) valid = false; else src = t - 1024; }
      if (valid) v = (float)y[src * 1365 + c];
    }
    yv[kk] = v;
    ss += v * v;
  }
  __shared__ float red[4];
  ss = wred_sum(ss);
  if ((tid & 63) == 0) red[tid >> 6] = ss;
  __syncthreads();
  ss = red[0] + red[1] + red[2] + red[3];
  const float r = sqrtf(1365.f) / fmaxf(sqrtf(ss), 1e-12f);
#pragma unroll
  for (int kk = 0; kk < 6; ++kk) {
    int c = kk * 256 + tid;
    if (c < 1365) yn[(size_t)t * 1376 + c] = (bf16_t)(yv[kk] * r * gamma[c]);
  }
  if (tid < 11) yn[(size_t)t * 1376 + 1365 + tid] = (bf16_t)0.f;
}

// ---------------- launcher ----------------
extern "C" void kernel_launch(void* const* d_in, const int* in_sizes, int n_in,
                              void* d_out, int out_size, void* d_ws, size_t ws_size,
                              hipStream_t stream) {
  const float* x        = (const float*)d_in[0];
  const float* sa_gamma = (const float*)d_in[1];
  const float* sa_wq    = (const float*)d_in[2];
  const float* sa_wkv   = (const float*)d_in[3];
  const float* sa_wo    = (const float*)d_in[4];
  const float* ta_gamma = (const float*)d_in[5];
  const float* ta_wq    = (const float*)d_in[6];
  const float* ta_wkv   = (const float*)d_in[7];
  const float* ta_wo    = (const float*)d_in[8];
  const float* sp_w1 = (const float*)d_in[9];
  const float* sp_b1 = (const float*)d_in[10];
  const float* sp_w2 = (const float*)d_in[11];
  const float* sp_b2 = (const float*)d_in[12];
  const float* sp_w3 = (const float*)d_in[13];
  const float* sp_b3 = (const float*)d_in[14];
  const float* tp_w1 = (const float*)d_in[15];
  const float* tp_b1 = (const float*)d_in[16];
  const float* tp_w2 = (const float*)d_in[17];
  const float* tp_b2 = (const float*)d_in[18];
  const float* tp_w3 = (const float*)d_in[19];
  const float* tp_b3 = (const float*)d_in[20];
  const float* ff_win   = (const float*)d_in[21];
  const float* ff_gamma = (const float*)d_in[22];
  const float* ff_wout  = (const float*)d_in[23];
  float* outp = (float*)d_out;

  char* ws = (char*)d_ws;
  size_t off = 0;
  auto alloc = [&](size_t bytes) -> char* {
    char* p = ws + off;
    off += (bytes + 255) & ~(size_t)255;
    return p;
  };
  const long T = 16384;
  float*  xs  = (float*)alloc((size_t)T * 512 * 4);    // residual stream
  bf16_t* xn  = (bf16_t*)alloc((size_t)T * 512 * 2);   // normed input | ob_s
  char*   R2  = alloc((size_t)T * 1536 * 2);           // qkv | FF: y (16384x1365 bf16)
  char*   R3  = alloc((size_t)T * 1536 * 2);           // vT (16M) | xt (33.5M)
  char*   R4  = alloc((size_t)T * 1376 * 2);           // ob_t (16M) | ynb (45M)
  bf16_t* wqkvT_sa = (bf16_t*)alloc(1536ULL * 512 * 2);
  bf16_t* woT_sa   = (bf16_t*)alloc(512ULL * 512 * 2);
  bf16_t* wqkvT_ta = (bf16_t*)alloc(1536ULL * 512 * 2);
  bf16_t* woT_ta   = (bf16_t*)alloc(512ULL * 512 * 2);
  bf16_t* winT  = (bf16_t*)alloc(2752ULL * 512 * 2);   // GeGLU-interleaved
  bf16_t* woutT = (bf16_t*)alloc(512ULL * 1376 * 2);
  bf16_t* tabb  = (bf16_t*)alloc(8 * 4000 * 2);
  float*  tabf  = (float*)alloc(8 * 15 * 4);

  bf16_t* qkv  = (bf16_t*)R2;
  bf16_t* ybuf = (bf16_t*)R2;    // FF pre-activated hidden (qkv dead)
  bf16_t* vT   = (bf16_t*)R3;
  float*  xt   = (float*)R3;     // temporal residual (vT dead after flash)
  bf16_t* ob_s = xn;             // spatial attn out reuses xn region
  bf16_t* ob_t = (bf16_t*)R4;    // temporal attn out
  bf16_t* ynb  = (bf16_t*)R4;    // normed FF hidden (ob_t dead)

  // 1) input: per b transpose (512 x 8192) -> (8192 x 512)
  st_transpose2d<<<dim3(256, 16, 2), 256, 0, stream>>>(x, xs, 512, 8192,
                                                       (long long)512 * 8192, (long long)512 * 8192);
  // 2) weight transposes
  auto wt = [&](const float* src, bf16_t* dst, int K, int Kpad, int N, int srcld, int coloff) {
    long tot = (long)N * Kpad;
    st_wtrans<<<dim3((tot + 255) / 256), 256, 0, stream>>>(src, dst, K, Kpad, N, srcld, coloff, tot);
  };
  wt(sa_wq, wqkvT_sa, 512, 512, 512, 512, 0);
  wt(sa_wkv, wqkvT_sa + 512 * 512, 512, 512, 1024, 1024, 0);
  wt(sa_wo, woT_sa, 512, 512, 512, 512, 0);
  wt(ta_wq, wqkvT_ta, 512, 512, 512, 512, 0);
  wt(ta_wkv, wqkvT_ta + 512 * 512, 512, 512, 1024, 1024, 0);
  wt(ta_wo, woT_ta, 512, 512, 512, 512, 0);
  st_wtrans_geglu<<<dim3((2752 * 512) / 256), 256, 0, stream>>>(ff_win, winT, 2752L * 512);
  wt(ff_wout, woutT, 1365, 1376, 512, 512, 0);
  // 3) CPB tables
  st_cpb<<<dim3(3969), 256, 0, stream>>>(sp_w1, sp_b1, sp_w2, sp_b2, sp_w3, sp_b3, tabb, tabf, 1);
  st_cpb<<<dim3(15), 256, 0, stream>>>(tp_w1, tp_b1, tp_w2, tp_b2, tp_w3, tp_b3, tabb, tabf, 0);

  // ---- spatial attention ----
  st_rmsnorm<<<dim3(4096), 256, 0, stream>>>(xs, sa_gamma, xn);
  st_gemm<1><<<dim3(128, 12, 1), 256, 0, stream>>>(
      xn, wqkvT_sa, (void*)qkv, nullptr, nullptr, 16384, 1536, 512, 512, 512, 1536, 1, 0, 0, 0, 0, 0, 0);
  st_vtrans<<<dim3(32, 2, 128), 256, 0, stream>>>(qkv, vT);
  st_flash<<<dim3(8, 128), 256, 0, stream>>>(qkv, vT, tabb, ob_s);
  // wo + residual + fused spatial->temporal permute  -> xt
  st_gemm<3><<<dim3(128, 4, 1), 256, 0, stream>>>(
      ob_s, woT_sa, (void*)xt, nullptr, xs, 16384, 512, 512, 512, 512, 512, 1, 0, 0, 0, 0, 0, 0);

  // ---- temporal attention ----
  st_rmsnorm<<<dim3(4096), 256, 0, stream>>>(xt, ta_gamma, xn);
  st_gemm<1><<<dim3(128, 12, 1), 256, 0, stream>>>(
      xn, wqkvT_ta, (void*)qkv, nullptr, nullptr, 16384, 1536, 512, 512, 512, 1536, 1, 0, 0, 0, 0, 0, 0);
  st_tattn2<<<dim3(4096), 256, 0, stream>>>(qkv, tabf, ob_t);
  // wo + residual + fused temporal->spatial permute -> xs (f32) + xn (bf16)
  st_gemm<4><<<dim3(128, 4, 1), 256, 0, stream>>>(
      ob_t, woT_ta, (void*)xs, (void*)xn, xt, 16384, 512, 512, 512, 512, 512, 1, 0, 0, 0, 0, 0, 0);

  // ---- feed-forward ----
  st_gemm<5><<<dim3(128, 22, 1), 256, 0, stream>>>(
      xn, winT, (void*)ybuf, nullptr, nullptr, 16384, 2752, 512, 512, 512, 1365, 1, 0, 0, 0, 0, 0, 0);
  st_glu<<<dim3(16384), 256, 0, stream>>>(ybuf, ff_gamma, ynb);
  st_gemm<2><<<dim3(128, 4, 1), 256, 0, stream>>>(
      ynb, woutT, (void*)xs, nullptr, xs, 16384, 512, 1376, 1376, 1376, 512, 1, 0, 0, 0, 0, 0, 0);

  // ---- output: per b transpose (8192 x 512) -> (512 x 8192) ----
  st_transpose2d<<<dim3(16, 256, 2), 256, 0, stream>>>(xs, outp, 8192, 512,
                                                       (long long)8192 * 512, (long long)8192 * 512);
}